// Round 4
// baseline (694.253 us; speedup 1.0000x reference)
//
#include <hip/hip_runtime.h>

// Problem dims (fixed by setup_inputs): B=4096, A=2048, F=8
#define NB    4096
#define AP1   2049            // A+1 rows per sample
#define FEAT  8
#define ROWF  (AP1 * FEAT)    // 16392 floats per sample
#define NCHUNK 4096           // float4 chunks in the action region (2048*8/4)

// ws layout (16 bytes, zeroed via hipMemsetAsync each launch, replays in graph):
//   ws[0] : sum_b (pred_count - targ_count)^2
//   ws[1] : sum_{valid b} per-sample mse
//   ws[2] : n_valid
//   ws[3] : finished-block counter (uint)

// R3 post-mortem: data-dependent trip count (nvec=count*2) made the compiler
// emit a serialized, VGPR-28, load-use-load-use loop -> ~1 TB/s latency-bound,
// plus count-proportional block imbalance. Fix: read the FULL action region
// (compile-time trip count, 16 chunks/thread, fully unrolled) and mask by
// i < nvec. 2x logical traffic but bandwidth-bound instead of latency-bound.
// Masked-out chunks add exact 0.0f in-order -> per-thread partial sums are
// bitwise identical to the count-bounded loop.

__global__ __launch_bounds__(256, 4) void loss_fused_kernel(
        const float* __restrict__ pred,
        const float* __restrict__ targ,
        float* __restrict__ ws,
        float* __restrict__ out) {
    const int b = blockIdx.x;
    const float* pb = pred + (size_t)b * ROWF;
    const float* tb = targ + (size_t)b * ROWF;

    const float tc = tb[0];      // target count (exact small integer in fp32)
    const float pc = pb[0];      // predicted count
    const int count = (int)tc;
    const int nvec = count * 2;  // valid float4 chunks

    const float4* p4 = (const float4*)(pb + FEAT);
    const float4* t4 = (const float4*)(tb + FEAT);

    float s = 0.0f;
    // 16 chunks/thread, stride 256, same visitation order as the old loop.
    #pragma unroll
    for (int u = 0; u < 4; ++u) {
        const int i0 = (int)threadIdx.x + u * 1024;
        const int i1 = i0 + 256;
        const int i2 = i0 + 512;
        const int i3 = i0 + 768;
        const float4 a0 = p4[i0];
        const float4 a1 = p4[i1];
        const float4 a2 = p4[i2];
        const float4 a3 = p4[i3];
        const float4 c0 = t4[i0];
        const float4 c1 = t4[i1];
        const float4 c2 = t4[i2];
        const float4 c3 = t4[i3];
        float dx, dy, dz, dw, q;
        dx = a0.x - c0.x; dy = a0.y - c0.y; dz = a0.z - c0.z; dw = a0.w - c0.w;
        q = dx * dx + dy * dy + dz * dz + dw * dw;
        s += (i0 < nvec) ? q : 0.0f;
        dx = a1.x - c1.x; dy = a1.y - c1.y; dz = a1.z - c1.z; dw = a1.w - c1.w;
        q = dx * dx + dy * dy + dz * dz + dw * dw;
        s += (i1 < nvec) ? q : 0.0f;
        dx = a2.x - c2.x; dy = a2.y - c2.y; dz = a2.z - c2.z; dw = a2.w - c2.w;
        q = dx * dx + dy * dy + dz * dz + dw * dw;
        s += (i2 < nvec) ? q : 0.0f;
        dx = a3.x - c3.x; dy = a3.y - c3.y; dz = a3.z - c3.z; dw = a3.w - c3.w;
        q = dx * dx + dy * dy + dz * dz + dw * dw;
        s += (i3 < nvec) ? q : 0.0f;
    }

    // block reduction
    #pragma unroll
    for (int o = 32; o > 0; o >>= 1) s += __shfl_down(s, o, 64);
    __shared__ float sm[4];
    const int wid  = threadIdx.x >> 6;
    const int lane = threadIdx.x & 63;
    if (lane == 0) sm[wid] = s;
    __syncthreads();

    if (threadIdx.x == 0) {
        const float total = sm[0] + sm[1] + sm[2] + sm[3];
        const float d = pc - tc;
        const bool valid = (count > 0);

        atomicAdd(&ws[0], d * d);
        if (valid) {
            atomicAdd(&ws[1], total / (float)(count * FEAT));
            atomicAdd(&ws[2], 1.0f);
        }
        __threadfence();
        const unsigned old = atomicAdd((unsigned*)(ws + 3), 1u);
        if (old == NB - 1) {
            const float count_sum = atomicAdd(&ws[0], 0.0f);
            const float mse_sum   = atomicAdd(&ws[1], 0.0f);
            const float nv        = atomicAdd(&ws[2], 0.0f);
            const float count_loss = count_sum * (1.0f / (float)NB);
            const float atl = (nv > 0.0f) ? (mse_sum / nv) : 0.0f;
            out[0] = count_loss + 2.0f * atl;  // W_ACTION_COUNT=1, W_ACTION_TENSOR=2
        }
    }
}

extern "C" void kernel_launch(void* const* d_in, const int* in_sizes, int n_in,
                              void* d_out, int out_size, void* d_ws, size_t ws_size,
                              hipStream_t stream) {
    const float* pred = (const float*)d_in[0];
    const float* targ = (const float*)d_in[1];
    float* out = (float*)d_out;
    float* ws  = (float*)d_ws;

    // Zero the 4 accumulator/counter slots; replays inside the graph.
    (void)hipMemsetAsync(ws, 0, 16, stream);
    loss_fused_kernel<<<NB, 256, 0, stream>>>(pred, targ, ws, out);
}

// Round 5
// 463.429 us; speedup vs baseline: 1.4981x; 1.4981x over previous
//
#include <hip/hip_runtime.h>

// Problem dims (fixed by setup_inputs): B=4096, A=2048, F=8
#define NB    4096
#define AP1   2049            // A+1 rows per sample
#define FEAT  8
#define ROWF  (AP1 * FEAT)    // 16392 floats per sample

// R4 post-mortem: the atomic-fused tail (R2-R4) put ~16K same-address
// device-scope RMWs on one cacheline -> ~260-350us serialized floor,
// independent of the loop. Reverted to the proven two-kernel structure
// (R0, 464us). ws layout (floats), every slot written each launch:
//   ws[0      .. NB)   per-sample (pred_count - targ_count)^2
//   ws[NB     .. 2NB)  per-sample mse (0 if count==0)
//   ws[2NB    .. 3NB)  per-sample valid flag (0/1)

__global__ __launch_bounds__(256) void loss_main_kernel(
        const float* __restrict__ pred,
        const float* __restrict__ targ,
        float* __restrict__ ws) {
    const int b = blockIdx.x;
    const float* pb = pred + (size_t)b * ROWF;
    const float* tb = targ + (size_t)b * ROWF;

    const float tc = tb[0];      // target count (exact small integer in fp32)
    const float pc = pb[0];      // predicted count
    const int count = (int)tc;

    // Actions region: floats [FEAT, FEAT + count*FEAT) — 16B-aligned,
    // count*FEAT divisible by 8 -> count*2 float4 chunks.
    const int nvec = count * 2;
    const float4* p4 = (const float4*)(pb + FEAT);
    const float4* t4 = (const float4*)(tb + FEAT);

    float s = 0.0f;
    int i = (int)threadIdx.x;
    const int stride = 256;

    // 4x unrolled. R3/R4 disasm-level evidence (VGPR 28/32) showed the
    // scheduler serializes these loads into load-use pairs -> ~2 outstanding
    // loads/wave -> latency-bound at ~1-3 TB/s. sched_barrier(0) after the
    // load block forbids the scheduler from sinking loads into the math:
    // all 8 dwordx4 issue back-to-back -> 8KB in flight per wave.
    for (; i + 3 * stride < nvec; i += 4 * stride) {
        const float4 a0 = p4[i];
        const float4 a1 = p4[i + stride];
        const float4 a2 = p4[i + 2 * stride];
        const float4 a3 = p4[i + 3 * stride];
        const float4 c0 = t4[i];
        const float4 c1 = t4[i + stride];
        const float4 c2 = t4[i + 2 * stride];
        const float4 c3 = t4[i + 3 * stride];
        __builtin_amdgcn_sched_barrier(0);
        float dx, dy, dz, dw;
        dx = a0.x - c0.x; dy = a0.y - c0.y; dz = a0.z - c0.z; dw = a0.w - c0.w;
        s += dx * dx + dy * dy + dz * dz + dw * dw;
        dx = a1.x - c1.x; dy = a1.y - c1.y; dz = a1.z - c1.z; dw = a1.w - c1.w;
        s += dx * dx + dy * dy + dz * dz + dw * dw;
        dx = a2.x - c2.x; dy = a2.y - c2.y; dz = a2.z - c2.z; dw = a2.w - c2.w;
        s += dx * dx + dy * dy + dz * dz + dw * dw;
        dx = a3.x - c3.x; dy = a3.y - c3.y; dz = a3.z - c3.z; dw = a3.w - c3.w;
        s += dx * dx + dy * dy + dz * dz + dw * dw;
    }
    for (; i < nvec; i += stride) {
        const float4 a = p4[i];
        const float4 c = t4[i];
        const float dx = a.x - c.x;
        const float dy = a.y - c.y;
        const float dz = a.z - c.z;
        const float dw = a.w - c.w;
        s += dx * dx + dy * dy + dz * dz + dw * dw;
    }

    // block reduction
    #pragma unroll
    for (int o = 32; o > 0; o >>= 1) s += __shfl_down(s, o, 64);
    __shared__ float sm[4];
    const int wid  = threadIdx.x >> 6;
    const int lane = threadIdx.x & 63;
    if (lane == 0) sm[wid] = s;
    __syncthreads();

    if (threadIdx.x == 0) {
        const float total = sm[0] + sm[1] + sm[2] + sm[3];
        const float d = pc - tc;
        ws[b] = d * d;
        const bool valid = (count > 0);
        ws[NB + b]     = valid ? (total / (float)(count * FEAT)) : 0.0f;
        ws[2 * NB + b] = valid ? 1.0f : 0.0f;
    }
}

__global__ __launch_bounds__(256) void reduce_kernel(
        const float* __restrict__ ws, float* __restrict__ out) {
    float s0 = 0.0f, s1 = 0.0f, s2 = 0.0f;
    for (int i = threadIdx.x; i < NB; i += 256) {
        s0 += ws[i];
        s1 += ws[NB + i];
        s2 += ws[2 * NB + i];
    }
    #pragma unroll
    for (int o = 32; o > 0; o >>= 1) {
        s0 += __shfl_down(s0, o, 64);
        s1 += __shfl_down(s1, o, 64);
        s2 += __shfl_down(s2, o, 64);
    }
    __shared__ float sm[3][4];
    const int wid  = threadIdx.x >> 6;
    const int lane = threadIdx.x & 63;
    if (lane == 0) { sm[0][wid] = s0; sm[1][wid] = s1; sm[2][wid] = s2; }
    __syncthreads();
    if (threadIdx.x == 0) {
        const float count_sum = sm[0][0] + sm[0][1] + sm[0][2] + sm[0][3];
        const float mse_sum   = sm[1][0] + sm[1][1] + sm[1][2] + sm[1][3];
        const float nv        = sm[2][0] + sm[2][1] + sm[2][2] + sm[2][3];
        const float count_loss = count_sum * (1.0f / (float)NB);
        const float atl = (nv > 0.0f) ? (mse_sum / nv) : 0.0f;
        out[0] = count_loss + 2.0f * atl;   // W_ACTION_COUNT=1, W_ACTION_TENSOR=2
    }
}

extern "C" void kernel_launch(void* const* d_in, const int* in_sizes, int n_in,
                              void* d_out, int out_size, void* d_ws, size_t ws_size,
                              hipStream_t stream) {
    const float* pred = (const float*)d_in[0];
    const float* targ = (const float*)d_in[1];
    float* out = (float*)d_out;
    float* ws  = (float*)d_ws;

    loss_main_kernel<<<NB, 256, 0, stream>>>(pred, targ, ws);
    reduce_kernel<<<1, 256, 0, stream>>>(ws, out);
}